// Round 7
// baseline (283.954 us; speedup 1.0000x reference)
//
#include <hip/hip_runtime.h>

// Weighted MSE loss:
//   bin i s.t. edge[i] < t <= edge[i+1]  -> weight[i]; outside -> 0
//   loss = sum(w * (p - t)^2) / sum(weights)
// R6: amortize per-wave overhead. R5 (flat, 2KB/wave) = 93us @2.9TB/s eff:
// wave lifetime dominated by reduce/barrier/atomic with no loads in flight.
// Now each block owns 32KB/array: 8 explicit float4 pairs in named regs,
// all 16 loads issued before any use, one reduce+plain-store per block.
// Grid 4096, partial[blockIdx.x] (ws, no atomic/zeroing), 1-block finish.

__device__ __forceinline__ float wmse_elem(float p, float t,
                                           float e0, float e1, float e2,
                                           float e3, float e4, float e5,
                                           float w0, float w1, float w2,
                                           float w3, float w4) {
    float w = 0.0f;
    w = (t > e0 && t <= e1) ? w0 : w;
    w = (t > e1 && t <= e2) ? w1 : w;
    w = (t > e2 && t <= e3) ? w2 : w;
    w = (t > e3 && t <= e4) ? w3 : w;
    w = (t > e4 && t <= e5) ? w4 : w;
    float d = p - t;
    return w * d * d;
}

#define WMSE4(p, t) (                                                          \
    wmse_elem((p).x, (t).x, e0, e1, e2, e3, e4, e5, w0, w1, w2, w3, w4) +      \
    wmse_elem((p).y, (t).y, e0, e1, e2, e3, e4, e5, w0, w1, w2, w3, w4) +      \
    wmse_elem((p).z, (t).z, e0, e1, e2, e3, e4, e5, w0, w1, w2, w3, w4) +      \
    wmse_elem((p).w, (t).w, e0, e1, e2, e3, e4, e5, w0, w1, w2, w3, w4))

#define PER_BLOCK_F4 2048LL   // 8 iters x 256 threads (32KB per array per block)

__global__ __launch_bounds__(256) void WeightedMSELoss_60335700574782_kernel(
    const float* __restrict__ pred, const float* __restrict__ targ,
    const float* __restrict__ edge, const float* __restrict__ weights,
    float* __restrict__ partial) {
    const float e0 = edge[0], e1 = edge[1], e2 = edge[2];
    const float e3 = edge[3], e4 = edge[4], e5 = edge[5];
    const float w0 = weights[0], w1 = weights[1], w2 = weights[2];
    const float w3 = weights[3], w4 = weights[4];

    const float4* __restrict__ p4 = (const float4*)pred;
    const float4* __restrict__ t4 = (const float4*)targ;
    const long long base = (long long)blockIdx.x * PER_BLOCK_F4 + threadIdx.x;

    // 16 loads issued before any use: 64 data VGPRs keep them all in flight.
    float4 pa = p4[base + 0 * 256];
    float4 ta = t4[base + 0 * 256];
    float4 pb = p4[base + 1 * 256];
    float4 tb = t4[base + 1 * 256];
    float4 pc = p4[base + 2 * 256];
    float4 tc = t4[base + 2 * 256];
    float4 pd = p4[base + 3 * 256];
    float4 td = t4[base + 3 * 256];
    float4 pe = p4[base + 4 * 256];
    float4 te = t4[base + 4 * 256];
    float4 pf = p4[base + 5 * 256];
    float4 tf = t4[base + 5 * 256];
    float4 pg = p4[base + 6 * 256];
    float4 tg = t4[base + 6 * 256];
    float4 ph = p4[base + 7 * 256];
    float4 th = t4[base + 7 * 256];

    float acc0 = WMSE4(pa, ta) + WMSE4(pe, te);
    float acc1 = WMSE4(pb, tb) + WMSE4(pf, tf);
    float acc2 = WMSE4(pc, tc) + WMSE4(pg, tg);
    float acc3 = WMSE4(pd, td) + WMSE4(ph, th);
    float acc = (acc0 + acc1) + (acc2 + acc3);

    // wave64 reduce
    #pragma unroll
    for (int off = 32; off > 0; off >>= 1)
        acc += __shfl_down(acc, off, 64);

    __shared__ float smem[4];  // 256 threads = 4 waves
    const int lane = threadIdx.x & 63;
    const int wid = threadIdx.x >> 6;
    if (lane == 0) smem[wid] = acc;
    __syncthreads();
    if (threadIdx.x == 0)
        partial[blockIdx.x] = smem[0] + smem[1] + smem[2] + smem[3];
}

__global__ __launch_bounds__(256) void wmse_finish_kernel(
    const float* __restrict__ partial, int nparts,
    const float* __restrict__ pred, const float* __restrict__ targ,
    const float* __restrict__ edge, const float* __restrict__ weights,
    float* __restrict__ out, long long tail_start, long long n) {
    const float e0 = edge[0], e1 = edge[1], e2 = edge[2];
    const float e3 = edge[3], e4 = edge[4], e5 = edge[5];
    const float w0 = weights[0], w1 = weights[1], w2 = weights[2];
    const float w3 = weights[3], w4 = weights[4];
    const float inv_wsum = 1.0f / (w0 + w1 + w2 + w3 + w4);

    float acc = 0.0f;
    for (int i = threadIdx.x; i < nparts; i += blockDim.x)
        acc += partial[i];

    // remainder elements not covered by full blocks (none at this N)
    for (long long j = tail_start + threadIdx.x; j < n; j += blockDim.x)
        acc += wmse_elem(pred[j], targ[j], e0, e1, e2, e3, e4, e5, w0, w1, w2, w3, w4);

    #pragma unroll
    for (int off = 32; off > 0; off >>= 1)
        acc += __shfl_down(acc, off, 64);

    __shared__ float smem[4];
    const int lane = threadIdx.x & 63;
    const int wid = threadIdx.x >> 6;
    if (lane == 0) smem[wid] = acc;
    __syncthreads();
    if (threadIdx.x == 0)
        out[0] = (smem[0] + smem[1] + smem[2] + smem[3]) * inv_wsum;
}

extern "C" void kernel_launch(void* const* d_in, const int* in_sizes, int n_in,
                              void* d_out, int out_size, void* d_ws, size_t ws_size,
                              hipStream_t stream) {
    const float* pred    = (const float*)d_in[0];
    const float* targ    = (const float*)d_in[1];
    const float* weights = (const float*)d_in[2];
    const float* edge    = (const float*)d_in[3];
    float* out = (float*)d_out;
    float* partial = (float*)d_ws;    // one float per block; written before read
    const long long n = (long long)in_sizes[0];
    const long long n4 = n >> 2;

    const int grid = (int)(n4 / PER_BLOCK_F4);          // 4096 at this N
    const long long tail_start = (long long)grid * PER_BLOCK_F4 * 4;

    if (grid > 0) {
        WeightedMSELoss_60335700574782_kernel<<<grid, 256, 0, stream>>>(
            pred, targ, edge, weights, partial);
    }
    wmse_finish_kernel<<<1, 256, 0, stream>>>(
        partial, grid, pred, targ, edge, weights, out, tail_start, n);
}